// Round 7
// baseline (175.231 us; speedup 1.0000x reference)
//
#include <hip/hip_runtime.h>
#include <math.h>

#define NGRAPH 256
#define NPG 256
#define HF 128
#define EPG 4096      // real edges per graph
#define CSLOTS 5136   // CSR slots: 4352 + 4-align padding + slack
#define FSTR 132      // f32 row stride in tbufF (aliases hpair)
#define PSTR 136      // short row stride in hpair

typedef __attribute__((ext_vector_type(8))) short bf16x8;
typedef __attribute__((ext_vector_type(4))) float f32x4;

static __device__ __forceinline__ unsigned bcu(float f){ return __builtin_bit_cast(unsigned, f); }
static __device__ __forceinline__ float bcf(unsigned u){ return __builtin_bit_cast(float, u); }
static __device__ __forceinline__ unsigned rtn16(float f){
  unsigned u = bcu(f);
  return (u + 0x7FFFu + ((u >> 16) & 1u)) >> 16;
}

// ---------------- W transpose + split to bf16 hi/lo: Wt[n][k] ----------------
__global__ __launch_bounds__(256) void prep_wt(const float* __restrict__ W1,
                                               const float* __restrict__ W2,
                                               const float* __restrict__ W3,
                                               short* __restrict__ Wt) {
  int idx = blockIdx.x * 256 + threadIdx.x;
  int L = idx >> 14, r = idx & 16383;
  int k = r >> 7, n = r & 127;
  const float* W = (L == 0) ? W1 : (L == 1) ? W2 : W3;
  float w = W[k*128 + n];
  unsigned hi = rtn16(w);
  float lo = w - bcf(hi << 16);
  short* Whi = Wt + (size_t)L * 2 * 16384;
  short* Wlo = Whi + 16384;
  Whi[n*128 + k] = (short)hi;
  Wlo[n*128 + k] = (short)(bcu(lo) >> 16);
}

// sort compare-exchange step (descending key, ascending idx on ties)
#define BSTEP(OK, OI, KKc, Jc) do { \
  bool iLess = ((tid & (Jc)) == 0); \
  bool descR = ((tid & (KKc)) == 0); \
  bool myFirst = (kf > (OK)) || (kf == (OK) && ki < (OI)); \
  bool keep = (iLess == descR) ? myFirst : !myFirst; \
  if (!keep) { kf = (OK); ki = (OI); } \
} while (0)

// wave0 scan: cnt -> 4-aligned rloc + rlen + self slot + curA
#define WAVE0_SCAN() do { \
  if (wid == 0) { \
    int b4 = lane*4; \
    int c0=cntA[b4+0], c1=cntA[b4+1], c2=cntA[b4+2], c3=cntA[b4+3]; \
    int a0=(c0+3)&~3, a1=(c1+3)&~3, a2=(c2+3)&~3, a3=(c3+3)&~3; \
    int tot=a0+a1+a2+a3; \
    int run=tot; \
    _Pragma("unroll") \
    for (int off=1; off<64; off<<=1) { \
      int u = __shfl_up(run, off); \
      run += (lane >= off) ? u : 0; \
    } \
    int st0 = run - tot; \
    int sts[4] = {st0, st0+a0, st0+a0+a1, st0+a0+a1+a2}; \
    int cs[4]  = {c0, c1, c2, c3}; \
    _Pragma("unroll") \
    for (int j=0;j<4;++j) { \
      int vv=b4+j; \
      rloc[vv]=(unsigned short)sts[j]; \
      rlen[vv]=(unsigned short)cs[j]; \
      if (cs[j] > 0) { colS[sts[j]] = (unsigned char)vv; curA[vv]=sts[j]+1; } \
      else curA[vv]=sts[j]; \
    } \
  } \
} while (0)

// ---------------- whole network, one block per graph ----------------
__global__ __launch_bounds__(1024, 4) void fused_net(
    const float* __restrict__ x,
    const int* __restrict__ srcI, const int* __restrict__ dstI,
    const short* __restrict__ WtAll,
    const float* __restrict__ b1, const float* __restrict__ Ws1, const float* __restrict__ bs1,
    const float* __restrict__ b2, const float* __restrict__ Ws2, const float* __restrict__ bs2,
    const float* __restrict__ b3, const float* __restrict__ Ws3, const float* __restrict__ bs3,
    const float* __restrict__ Wl1, const float* __restrict__ bl1,
    const float* __restrict__ Wl2, const float* __restrict__ bl2,
    const float* __restrict__ Wl3, const float* __restrict__ bl3,
    float* __restrict__ out)
{
  __shared__ __align__(16) short hpair[2][NPG*PSTR];   // 139264 B; aliased by tbufF
  __shared__ __align__(4) unsigned char colS[CSLOTS];  // compacted CSR, 4-aligned rows, self incl
  __shared__ unsigned short rloc[NPG];                 // row start (4-aligned)
  __shared__ unsigned short rlen[NPG];                 // true row length (incl self)
  __shared__ unsigned mbits[8];                        // survivor bitmask
  __shared__ float dinv[NPG];
  __shared__ __align__(16) float bvec[HF];
  __shared__ __align__(16) float wsv[HF];
  __shared__ float score[NPG];
  __shared__ float tscale[NPG];                        // tq scratch / tanh scale
  __shared__ float nmf[NPG];
  __shared__ float skey[NPG];
  __shared__ int   sidx[NPG];
  __shared__ __align__(16) float red[1024];            // readout / MLP scratch
  __shared__ float zacc[2*HF];

  float* tbufF = (float*)&hpair[0][0];                 // [node][FSTR] f32 (G rows), alias
  short* hp0 = &hpair[0][0];
  short* hp1 = &hpair[1][0];
  int* cntA = (int*)skey;                              // CSR-build aliases (sort idle)
  int* curA = sidx;

  int tid = threadIdx.x;
  int g = blockIdx.x;
  size_t nbase = (size_t)g * NPG;
  int lane = tid & 63, wid = tid >> 6;

  // ---- stage x into bf16 hi/lo pair ----
  const float4* X4 = (const float4*)(x + nbase*HF);
  #pragma unroll
  for (int i = 0; i < 8; ++i) {
    int f4 = tid + i*1024;
    int r = f4 >> 5, kq = f4 & 31;
    float4 val = X4[f4];
    unsigned rx = rtn16(val.x), ry = rtn16(val.y), rz = rtn16(val.z), rw = rtn16(val.w);
    uint2 ph; ph.x = rx | (ry << 16); ph.y = rz | (rw << 16);
    float lx = val.x - bcf(rx << 16), ly = val.y - bcf(ry << 16);
    float lz = val.z - bcf(rz << 16), lw = val.w - bcf(rw << 16);
    uint2 pl; pl.x = (bcu(lx) >> 16) | (bcu(ly) & 0xFFFF0000u);
    pl.y = (bcu(lz) >> 16) | (bcu(lw) & 0xFFFF0000u);
    *(uint2*)&hp0[r*PSTR + kq*4] = ph;
    *(uint2*)&hp1[r*PSTR + kq*4] = pl;
  }

  // ---- edges into registers (kept all layers) ----
  int nb = g * NPG;
  int dloc[4], sloc[4];
  #pragma unroll
  for (int it = 0; it < 4; ++it) {
    int e = g*EPG + tid + it*1024;
    dloc[it] = dstI[e] - nb;
    sloc[it] = srcI[e] - nb;
  }

  // ---- initial CSR build ----
  if (tid < NPG) cntA[tid] = 1;                        // self
  if (tid < 8) mbits[tid] = 0xFFFFFFFFu;
  __syncthreads();
  #pragma unroll
  for (int it = 0; it < 4; ++it) atomicAdd(&cntA[dloc[it]], 1);
  __syncthreads();
  WAVE0_SCAN();
  __syncthreads();
  #pragma unroll
  for (int it = 0; it < 4; ++it) {
    int slot = atomicAdd(&curA[dloc[it]], 1);
    colS[slot] = (unsigned char)sloc[it];
  }

  // ---- 3 GCN+SAGPool layers ----
  #pragma unroll 1
  for (int L = 0; L < 3; ++L) {
    const short* Whi = WtAll + (size_t)L * 2 * 16384;
    const short* Wlo = Whi + 16384;
    const float* bias = (L == 0) ? b1 : (L == 1) ? b2 : b3;
    const float* Wsc  = (L == 0) ? Ws1 : (L == 1) ? Ws2 : Ws3;
    const float* bscp = (L == 0) ? bs1 : (L == 1) ? bs2 : bs3;
    int K = NPG >> (L + 1);          // 128, 64, 32

    __syncthreads();   // B0: pack + CSR (re)build complete

    // ---- params + dinv (row length IS degree incl self; 0 = dead) ----
    if (tid < HF) { bvec[tid] = bias[tid]; wsv[tid] = Wsc[tid]; }
    if (tid < NPG) {
      int c = rlen[tid];
      dinv[tid] = c ? (1.0f / sqrtf((float)c)) : 0.0f;
    }

    // ---- transform: G = dinv * (h @ W)  (MFMA on resident bf16 pair, in place) ----
    {
      int rg = wid & 7, cg = wid >> 3;
      int lr = lane & 15, lk8 = (lane >> 4) * 8;
      f32x4 tacc[2][4] = {};
      #pragma unroll
      for (int kc = 0; kc < 4; ++kc) {
        int k0 = kc*32 + lk8;
        bf16x8 ah[2], al[2];
        #pragma unroll
        for (int rt = 0; rt < 2; ++rt) {
          int row = rg*32 + rt*16 + lr;
          ah[rt] = *(const bf16x8*)&hp0[row*PSTR + k0];
          al[rt] = *(const bf16x8*)&hp1[row*PSTR + k0];
        }
        #pragma unroll
        for (int ct = 0; ct < 4; ++ct) {
          int n = cg*64 + ct*16 + lr;
          bf16x8 bh = *(const bf16x8*)&Whi[n*HF + k0];
          bf16x8 bl = *(const bf16x8*)&Wlo[n*HF + k0];
          #pragma unroll
          for (int rt = 0; rt < 2; ++rt) {
            tacc[rt][ct] = __builtin_amdgcn_mfma_f32_16x16x32_bf16(ah[rt], bh, tacc[rt][ct], 0, 0, 0);
            tacc[rt][ct] = __builtin_amdgcn_mfma_f32_16x16x32_bf16(al[rt], bh, tacc[rt][ct], 0, 0, 0);
            tacc[rt][ct] = __builtin_amdgcn_mfma_f32_16x16x32_bf16(ah[rt], bl, tacc[rt][ct], 0, 0, 0);
          }
        }
      }
      __syncthreads();   // B1: all pair reads done (dinv also complete)
      #pragma unroll
      for (int rt = 0; rt < 2; ++rt) {
        int row0 = rg*32 + rt*16 + (lane >> 4)*4;
        float d0 = dinv[row0+0], d1 = dinv[row0+1], d2 = dinv[row0+2], d3 = dinv[row0+3];
        #pragma unroll
        for (int ct = 0; ct < 4; ++ct) {
          int c = cg*64 + ct*16 + (lane & 15);
          tbufF[(row0+0)*FSTR + c] = tacc[rt][ct][0] * d0;
          tbufF[(row0+1)*FSTR + c] = tacc[rt][ct][1] * d1;
          tbufF[(row0+2)*FSTR + c] = tacc[rt][ct][2] * d2;
          tbufF[(row0+3)*FSTR + c] = tacc[rt][ct][3] * d3;
        }
      }
    }
    __syncthreads();   // B2: G ready

    // ---- aggregation: wave-per-node broadcast gather (conflict-free) ----
    // lane l holds cols 2l, 2l+1; 16 nodes per wave; fused relu + score partial.
    float2 bv2, wv2;
    bv2.x = bvec[2*lane]; bv2.y = bvec[2*lane+1];
    wv2.x = wsv[2*lane];  wv2.y = wsv[2*lane+1];
    if (tid < NPG) nmf[tid] = 0.f;
    float2 hacc[16];
    const unsigned* c32 = (const unsigned*)colS;
    int lofs = 2*lane;
    #pragma unroll
    for (int nn = 0; nn < 16; ++nn) {
      int vv = wid*16 + nn;
      int e0  = __builtin_amdgcn_readfirstlane((int)rloc[vv]);
      int len = __builtin_amdgcn_readfirstlane((int)rlen[vv]);
      int nc = (len + 3) >> 2;
      int cbase = e0 >> 2;
      float2 a; a.x = 0.f; a.y = 0.f;
      for (int c = 0; c < nc; ++c) {
        unsigned cw = __builtin_amdgcn_readfirstlane(c32[cbase + c]);
        int rem = len - (c << 2);
        {
          const float2 t = *(const float2*)&tbufF[(cw & 255u)*FSTR + lofs];
          a.x += t.x; a.y += t.y;
        }
        if (rem > 1) {
          const float2 t = *(const float2*)&tbufF[((cw >> 8) & 255u)*FSTR + lofs];
          a.x += t.x; a.y += t.y;
        }
        if (rem > 2) {
          const float2 t = *(const float2*)&tbufF[((cw >> 16) & 255u)*FSTR + lofs];
          a.x += t.x; a.y += t.y;
        }
        if (rem > 3) {
          const float2 t = *(const float2*)&tbufF[(cw >> 24)*FSTR + lofs];
          a.x += t.x; a.y += t.y;
        }
      }
      float dv = dinv[vv];
      a.x = fmaxf(fmaf(dv, a.x, bv2.x), 0.f);
      a.y = fmaxf(fmaf(dv, a.y, bv2.y), 0.f);
      hacc[nn] = a;
      float p = a.x*wv2.x + a.y*wv2.y;
      #pragma unroll
      for (int o = 32; o > 0; o >>= 1) p += __shfl_xor(p, o);
      if (lane == 0) tscale[vv] = p * dv;     // tq = (h.Ws)*dinv
    }
    __syncthreads();   // B3: tq ready, G reads done

    // ---- score aggregation: wave-per-node, lane-per-edge ----
    {
      float bsc = bscp[0];
      #pragma unroll
      for (int nn = 0; nn < 16; ++nn) {
        int vv = wid*16 + nn;
        int e0  = __builtin_amdgcn_readfirstlane((int)rloc[vv]);
        int len = __builtin_amdgcn_readfirstlane((int)rlen[vv]);
        float t = (lane < len) ? tscale[colS[e0 + lane]] : 0.f;
        if (len > 64) t += (lane + 64 < len) ? tscale[colS[e0 + 64 + lane]] : 0.f;
        #pragma unroll
        for (int o = 32; o > 0; o >>= 1) t += __shfl_xor(t, o);
        if (lane == 0) score[vv] = dinv[vv]*t + bsc;
      }
    }
    __syncthreads();   // B4: scores ready

    // ---- register bitonic top-K (4 waves), desc score / asc idx ----
    float kf = -INFINITY; int ki = tid;
    if (tid < NPG) {
      kf = (dinv[tid] > 0.f) ? score[tid] : -INFINITY;
      for (int kk = 2; kk <= 64; kk <<= 1)
        for (int j = kk >> 1; j > 0; j >>= 1) {
          float ok = __shfl_xor(kf, j);
          int   oi = __shfl_xor(ki, j);
          BSTEP(ok, oi, kk, j);
        }
    }
    if (tid < NPG) { skey[tid] = kf; sidx[tid] = ki; }
    else if (tid < NPG + 8) mbits[tid - NPG] = 0u;     // clear mask mid-sort (idle waves)
    __syncthreads();
    if (tid < NPG) {
      int l = tid ^ 64; float ok = skey[l]; int oi = sidx[l];
      BSTEP(ok, oi, 128, 64);
      for (int j = 32; j > 0; j >>= 1) {
        float sk = __shfl_xor(kf, j); int si = __shfl_xor(ki, j);
        BSTEP(sk, si, 128, j);
      }
    }
    __syncthreads();
    if (tid < NPG) { skey[tid] = kf; sidx[tid] = ki; }
    __syncthreads();
    if (tid < NPG) {
      int l = tid ^ 128; float ok = skey[l]; int oi = sidx[l];
      BSTEP(ok, oi, 256, 128);
    }
    __syncthreads();
    if (tid < NPG) { skey[tid] = kf; sidx[tid] = ki; }
    __syncthreads();
    if (tid < NPG) {
      int l = tid ^ 64; float ok = skey[l]; int oi = sidx[l];
      BSTEP(ok, oi, 256, 64);
      for (int j = 32; j > 0; j >>= 1) {
        float sk = __shfl_xor(kf, j); int si = __shfl_xor(ki, j);
        BSTEP(sk, si, 256, j);
      }
    }
    if (tid < K) { nmf[ki] = 1.0f; atomicOr(&mbits[ki>>5], 1u << (ki&31)); }
    __syncthreads();
    if (tid < NPG) tscale[tid] = tanhf(score[tid]) * nmf[tid];
    __syncthreads();

    // ---- write scaled h (f32) for readout ----
    #pragma unroll
    for (int nn = 0; nn < 16; ++nn) {
      int vv = wid*16 + nn;
      float ts = tscale[vv];
      float2 a = hacc[nn];
      a.x *= ts; a.y *= ts;
      hacc[nn] = a;
      *(float2*)&tbufF[vv*FSTR + lofs] = a;
    }
    __syncthreads();   // B6: scaled h ready

    // ---- readout: max & mean over selected nodes -> zacc ----
    {
      int f = tid & 127, vg = tid >> 7;
      float mx = -INFINITY, sm = 0.f;
      for (int vr = 0; vr < 32; ++vr) {
        int vv = vg*32 + vr;
        float val = tbufF[vv*FSTR + f];
        if (nmf[vv] > 0.f) { mx = fmaxf(mx, val); sm += val; }
      }
      red[vg*HF + f] = mx;
      __syncthreads();
      if (tid < HF) {
        float zm = red[tid];
        #pragma unroll
        for (int q = 1; q < 8; ++q) zm = fmaxf(zm, red[q*HF + tid]);
        if (L == 0) zacc[tid] = zm; else zacc[tid] += zm;
      }
      __syncthreads();
      red[vg*HF + f] = sm;
      __syncthreads();
      if (tid < HF) {
        float zs = red[tid];
        #pragma unroll
        for (int q = 1; q < 8; ++q) zs += red[q*HF + tid];
        float mn = zs / (float)K;
        if (L == 0) zacc[HF + tid] = mn; else zacc[HF + tid] += mn;
      }
      __syncthreads();   // tbufF reads done
    }

    if (L < 2) {
      // ---- pack scaled h into bf16 pair (after readout: tbufF alias safe) ----
      #pragma unroll
      for (int nn = 0; nn < 16; ++nn) {
        int vv = wid*16 + nn;
        float2 a = hacc[nn];
        unsigned rx = rtn16(a.x), ry = rtn16(a.y);
        unsigned ph = rx | (ry << 16);
        float lx = a.x - bcf(rx << 16), ly = a.y - bcf(ry << 16);
        unsigned pl = (bcu(lx) >> 16) | (bcu(ly) & 0xFFFF0000u);
        *(unsigned*)&hp0[vv*PSTR + lofs] = ph;
        *(unsigned*)&hp1[vv*PSTR + lofs] = pl;
      }

      // ---- rebuild compacted CSR (both endpoints alive) ----
      bool keep[4];
      #pragma unroll
      for (int it = 0; it < 4; ++it) {
        keep[it] = (((mbits[dloc[it]>>5] >> (dloc[it]&31)) & 1) &
                    ((mbits[sloc[it]>>5] >> (sloc[it]&31)) & 1)) != 0;
      }
      if (tid < NPG) cntA[tid] = (int)((mbits[tid>>5] >> (tid&31)) & 1);
      __syncthreads();
      #pragma unroll
      for (int it = 0; it < 4; ++it)
        if (keep[it]) atomicAdd(&cntA[dloc[it]], 1);
      __syncthreads();
      WAVE0_SCAN();
      __syncthreads();
      #pragma unroll
      for (int it = 0; it < 4; ++it) {
        if (keep[it]) {
          int slot = atomicAdd(&curA[dloc[it]], 1);
          colS[slot] = (unsigned char)sloc[it];
        }
      }
      // next-layer B0 covers completion
    }
  }

  __syncthreads();

  // ---- MLP head + log_softmax ----
  {
    int o = tid & 127, kg = tid >> 7;
    float p = 0.f;
    int k0 = kg*32;
    for (int k = k0; k < k0+32; ++k) p += zacc[k]*Wl1[k*HF + o];
    red[kg*HF + o] = p;
    __syncthreads();
    if (tid < HF) {
      float a = bl1[tid];
      #pragma unroll
      for (int q = 0; q < 8; ++q) a += red[q*HF + tid];
      score[tid] = fmaxf(a, 0.f);       // h1
    }
    __syncthreads();
    if (tid < 512) {
      int o2 = tid & 63, kg2 = tid >> 6;
      float p2 = 0.f;
      int k0b = kg2*16;
      for (int k = k0b; k < k0b+16; ++k) p2 += score[k]*Wl2[k*64 + o2];
      red[kg2*64 + o2] = p2;
    }
    __syncthreads();
    if (tid < 64) {
      float a = bl2[tid];
      #pragma unroll
      for (int q = 0; q < 8; ++q) a += red[q*64 + tid];
      tscale[tid] = fmaxf(a, 0.f);      // h2
    }
    __syncthreads();
    if (tid < 10) {
      float a = bl3[tid];
      for (int k = 0; k < 64; ++k) a += tscale[k]*Wl3[k*10 + tid];
      nmf[tid] = fmaxf(a, 0.f);         // logits
    }
    __syncthreads();
    if (tid == 0) {
      float m = nmf[0];
      for (int i = 1; i < 10; ++i) m = fmaxf(m, nmf[i]);
      float s = 0.f;
      for (int i = 0; i < 10; ++i) s += expf(nmf[i] - m);
      red[0] = m; red[1] = logf(s);
    }
    __syncthreads();
    if (tid < 10) out[(size_t)g*10 + tid] = nmf[tid] - red[0] - red[1];
  }
}

extern "C" void kernel_launch(void* const* d_in, const int* in_sizes, int n_in,
                              void* d_out, int out_size, void* d_ws, size_t ws_size,
                              hipStream_t stream) {
  const float* x   = (const float*)d_in[0];
  const int*  srcI = (const int*)d_in[1];
  const int*  dstI = (const int*)d_in[2];
  const float* W1  = (const float*)d_in[3];
  const float* b1  = (const float*)d_in[4];
  const float* W2  = (const float*)d_in[5];
  const float* b2  = (const float*)d_in[6];
  const float* W3  = (const float*)d_in[7];
  const float* b3  = (const float*)d_in[8];
  const float* Ws1 = (const float*)d_in[9];
  const float* bs1 = (const float*)d_in[10];
  const float* Ws2 = (const float*)d_in[11];
  const float* bs2 = (const float*)d_in[12];
  const float* Ws3 = (const float*)d_in[13];
  const float* bs3 = (const float*)d_in[14];
  const float* Wl1 = (const float*)d_in[15];
  const float* bl1 = (const float*)d_in[16];
  const float* Wl2 = (const float*)d_in[17];
  const float* bl2 = (const float*)d_in[18];
  const float* Wl3 = (const float*)d_in[19];
  const float* bl3 = (const float*)d_in[20];
  float* out = (float*)d_out;

  short* WtAll = (short*)d_ws;   // 3 * 2 * 16384 shorts = 192 KB

  prep_wt<<<192, 256, 0, stream>>>(W1, W2, W3, WtAll);
  fused_net<<<NGRAPH, 1024, 0, stream>>>(x, srcI, dstI, WtAll,
                                         b1, Ws1, bs1, b2, Ws2, bs2, b3, Ws3, bs3,
                                         Wl1, bl1, Wl2, bl2, Wl3, bl3, out);
}